// Round 10
// baseline (202.562 us; speedup 1.0000x reference)
//
#include <hip/hip_runtime.h>
#include <hip/hip_bf16.h>

// Problem constants: G=64, C=32, L=128, D=64, H=128, NCLS=10
#define NSEQ 2048   // G*C
#define LSEQ 128
#define DIN  64
#define HID  128
#define NCLS 10
#define XPAD 72     // padded x row (shorts)
#define HXP  72     // padded half-h row (64 cols + pad, shorts)
#define CHK  16     // timesteps staged per chunk

typedef __attribute__((ext_vector_type(8))) short bfrag8;   // 8 bf16 (MFMA A/B frag)
typedef __attribute__((ext_vector_type(4))) float facc4;    // MFMA C/D frag

__device__ __forceinline__ short f2bf(float f) {
    union { __hip_bfloat16 b; short s; } u;
    u.b = __float2bfloat16(f);   // RNE
    return u.s;
}

__device__ __forceinline__ bfrag8 load_bf16_frag(const float* __restrict__ p) {
    bfrag8 r;
#pragma unroll
    for (int j = 0; j < 8; ++j) r[j] = f2bf(p[j]);
    return r;
}

__device__ __forceinline__ float fast_sigmoid(float x) {
    float e = __builtin_amdgcn_exp2f(-1.4426950408889634f * x);
    return __builtin_amdgcn_rcpf(1.0f + e);
}
__device__ __forceinline__ float fast_tanh(float x) {
    float e = __builtin_amdgcn_exp2f(2.8853900817779268f * x);
    return 1.0f - 2.0f * __builtin_amdgcn_rcpf(1.0f + e);
}

// Raw block barrier: LDS-visibility only (R2/R9-validated on this structure).
__device__ __forceinline__ void block_barrier() {
    asm volatile("s_waitcnt lgkmcnt(0)" ::: "memory");
    __builtin_amdgcn_s_barrier();
    asm volatile("" ::: "memory");
}

// 2-unit LSTM cell (lane owns seqs 2qd / 2qd+1 at col khid)
__device__ __forceinline__ void lstm_cell(const float u0[4], const float u1[4],
                                          float cst[2], float hsum[2], short hb[2]) {
#pragma unroll
    for (int j = 0; j < 2; ++j) {
        const float* u = j ? u1 : u0;
        float iv = fast_sigmoid(u[0]);
        float fv = fast_sigmoid(u[1]);
        float gv = fast_tanh(u[2]);
        float ov = fast_sigmoid(u[3]);
        float c  = fv * cst[j] + iv * gv;
        cst[j]   = c;
        float hv = ov * fast_tanh(c);
        hsum[j] += hv;
        hb[j]    = f2bf(hv);
    }
}

// TWO-PHASE K-SPLIT PIPELINE. One block = 8 seqs, 8 waves, 2x row-dup map
// (R7). Hidden state split by column: waves 0-3 (group A) own h cols 0-63,
// waves 4-7 (B) own cols 64-127. Each timestep = 2 barrier regions:
//   phase0 (region 2t):   B: cell(t-1) from held acc, write h_B(t).
//                         ALL: part1 MFMAs (h_A(t) @ W[k0=0,1]) + x-MFMAs(t+1).
//   phase1 (region 2t+1): ALL: part2 MFMAs (h_B(t) @ W[k0=2,3]) -> u(t) done.
//                         A: cell(t) immediately, write h_A(t+1). B: defer.
// Each SIMD hosts one A + one B wave -> in every region one wave MFMA-issues
// while the other runs its trans-heavy cell: the phases de-lockstep and the
// matrix/VALU pipes overlap instead of time-slicing (the measured 2200-cy
// step vs 931-cy MFMA + 840-cy VALU accounting gap).
// Accumulation order (k0 ascending) is bit-identical to R7.
__global__ __launch_bounds__(512) void lstm_fused(
    const float* __restrict__ x,      // [2048][128][64] f32
    const float* __restrict__ Wih,    // [512][64] f32
    const float* __restrict__ Whh,    // [512][128] f32
    const float* __restrict__ bih,    // [512] f32
    const float* __restrict__ bhh,    // [512] f32
    float* __restrict__ rep)          // [2048][128] f32 (d_ws)
{
    __shared__ __align__(16) __hip_bfloat16 hbA[2][8][HXP];            // 2304 B
    __shared__ __align__(16) __hip_bfloat16 hbB[2][8][HXP];            // 2304 B
    __shared__ __align__(16) __hip_bfloat16 xs[2][CHK][8][XPAD];       // 36864 B

    const int tid  = threadIdx.x;
    const int w    = tid >> 6;
    const int lane = tid & 63;
    const int ln   = lane & 15;
    const int qd   = lane >> 4;
    const int s0   = blockIdx.x * 8;
    const int khid = w * 16 + ln;      // A waves: 0-63, B waves: 64-127
    const int khb  = khid & 63;        // column within the group's half-buffer
    const int arow = ln >> 1;          // A-side LDS row: seq of M-row ln
    const int sq0  = 2 * qd;
    const int sq1  = 2 * qd + 1;

    // ---- weight B-fragments: f32 -> bf16 registers (reused all 128 steps) ----
    bfrag8 whh[4][4];
    bfrag8 wih[4][2];
    facc4  biasf[4];    // bias as persistent MFMA C-input
#pragma unroll
    for (int g = 0; g < 4; ++g) {
        const int col = g * HID + khid;
        const float b = bih[col] + bhh[col];
        biasf[g] = (facc4){b, b, b, b};
#pragma unroll
        for (int k0 = 0; k0 < 4; ++k0)
            whh[g][k0] = load_bf16_frag(Whh + col * HID + k0 * 32 + qd * 8);
#pragma unroll
        for (int k0 = 0; k0 < 2; ++k0)
            wih[g][k0] = load_bf16_frag(Wih + col * DIN + k0 * 32 + qd * 8);
    }

    // zero both parities of both half-h buffers (h(0) = 0)
    {
        unsigned int* pa = (unsigned int*)&hbA[0][0][0];
        for (int i = tid; i < 2 * 8 * HXP / 2; i += 512) pa[i] = 0u;
        unsigned int* pb = (unsigned int*)&hbB[0][0][0];
        for (int i = tid; i < 2 * 8 * HXP / 2; i += 512) pb[i] = 0u;
    }

    // x staging: wave w stages sequence s0+w; lane covers 16 consecutive f32.
    const float* xsrc = x + (size_t)(s0 + w) * (LSEQ * DIN) + lane * 16;
    const int stt = lane >> 2;
    const int sdd = (lane & 3) * 16;

    {   // stage chunk 0
        float4 a0 = ((const float4*)xsrc)[0];
        float4 a1 = ((const float4*)xsrc)[1];
        float4 a2 = ((const float4*)xsrc)[2];
        float4 a3 = ((const float4*)xsrc)[3];
        bfrag8 o0, o1;
#pragma unroll
        for (int j = 0; j < 4; ++j) { o0[j] = f2bf(((float*)&a0)[j]); o0[4+j] = f2bf(((float*)&a1)[j]); }
#pragma unroll
        for (int j = 0; j < 4; ++j) { o1[j] = f2bf(((float*)&a2)[j]); o1[4+j] = f2bf(((float*)&a3)[j]); }
        *(bfrag8*)&xs[0][stt][w][sdd]     = o0;
        *(bfrag8*)&xs[0][stt][w][sdd + 8] = o1;
    }

    float cst[2]  = {0.f, 0.f};
    float hsum[2] = {0.f, 0.f};

    block_barrier();

    // prologue: acc for t=0 = bias + x(0) @ Wih^T  (dup rows ln>>1)
    facc4 accA[4], accB[4];
    {
        bfrag8 x0 = *(const bfrag8*)(&xs[0][0][arow][qd * 8]);
        bfrag8 x1 = *(const bfrag8*)(&xs[0][0][arow][32 + qd * 8]);
#pragma unroll
        for (int g = 0; g < 4; ++g) {
            accA[g] = __builtin_amdgcn_mfma_f32_16x16x32_bf16(x0, wih[g][0], biasf[g], 0, 0, 0);
            accA[g] = __builtin_amdgcn_mfma_f32_16x16x32_bf16(x1, wih[g][1], accA[g], 0, 0, 0);
        }
    }

    int cur = 0;

// ISA: 1 = group A wave (w<4), 0 = group B. FIRST: compile-time (ct==0).
#define STEP(ACCIN, ACCOUT, CT, ISA, FIRST)                                              \
    {                                                                                    \
        const int ct   = (CT);                                                           \
        const int nbuf = (ct < CHK - 1) ? buf : (buf ^ 1);                               \
        const int nct  = (ct + 1) & (CHK - 1);                                           \
        /* ================= phase 0 (region 2t) ================= */                    \
        if (!ISA) {   /* B: cell(t-1) from held ACCOUT (register-ready) */               \
            if (!(FIRST && chunk == 0)) {                                                \
                float u0[4], u1[4];                                                      \
                _Pragma("unroll")                                                        \
                for (int g = 0; g < 4; ++g) { u0[g] = ACCOUT[g][0]; u1[g] = ACCOUT[g][2]; } \
                short hb[2];                                                             \
                lstm_cell(u0, u1, cst, hsum, hb);                                        \
                ((short*)&hbB[cur][sq0][0])[khb] = hb[0];   /* h_B(t) -> read phase1 */  \
                ((short*)&hbB[cur][sq1][0])[khb] = hb[1];                                \
            }                                                                            \
        }                                                                                \
        {                                                                                \
            bfrag8 hfA0 = *(const bfrag8*)(&hbA[cur][arow][qd * 8]);                     \
            bfrag8 hfA1 = *(const bfrag8*)(&hbA[cur][arow][32 + qd * 8]);                \
            xf0 = *(const bfrag8*)(&xs[nbuf][nct][arow][qd * 8]);                        \
            xf1 = *(const bfrag8*)(&xs[nbuf][nct][arow][32 + qd * 8]);                   \
            _Pragma("unroll")                                                            \
            for (int g = 0; g < 4; ++g) {                                                \
                ACCIN[g] = __builtin_amdgcn_mfma_f32_16x16x32_bf16(hfA0, whh[g][0], ACCIN[g], 0, 0, 0); \
                ACCIN[g] = __builtin_amdgcn_mfma_f32_16x16x32_bf16(hfA1, whh[g][1], ACCIN[g], 0, 0, 0); \
            }                                                                            \
            /* x-part for t+1 (independent; B consumed ACCOUT above) */                  \
            _Pragma("unroll")                                                            \
            for (int g = 0; g < 4; ++g) {                                                \
                ACCOUT[g] = __builtin_amdgcn_mfma_f32_16x16x32_bf16(xf0, wih[g][0], biasf[g], 0, 0, 0); \
                ACCOUT[g] = __builtin_amdgcn_mfma_f32_16x16x32_bf16(xf1, wih[g][1], ACCOUT[g], 0, 0, 0); \
            }                                                                            \
        }                                                                                \
        if (ct == 0 && more) {      /* issue next chunk's global loads */                \
            const float* p = xsrc + (chunk + 1) * (CHK * DIN);                           \
            l0 = ((const float4*)p)[0];                                                  \
            l1 = ((const float4*)p)[1];                                                  \
            l2 = ((const float4*)p)[2];                                                  \
            l3 = ((const float4*)p)[3];                                                  \
        }                                                                                \
        block_barrier();                                                                 \
        /* ================= phase 1 (region 2t+1) ================= */                  \
        {                                                                                \
            bfrag8 hfB0 = *(const bfrag8*)(&hbB[cur][arow][qd * 8]);                     \
            bfrag8 hfB1 = *(const bfrag8*)(&hbB[cur][arow][32 + qd * 8]);                \
            _Pragma("unroll")                                                            \
            for (int g = 0; g < 4; ++g) {                                                \
                ACCIN[g] = __builtin_amdgcn_mfma_f32_16x16x32_bf16(hfB0, whh[g][2], ACCIN[g], 0, 0, 0); \
                ACCIN[g] = __builtin_amdgcn_mfma_f32_16x16x32_bf16(hfB1, whh[g][3], ACCIN[g], 0, 0, 0); \
            }                                                                            \
        }                                                                                \
        if (ISA) {    /* A: cell(t) now; write h_A(t+1) for next phase0 */               \
            float u0[4], u1[4];                                                          \
            _Pragma("unroll")                                                            \
            for (int g = 0; g < 4; ++g) { u0[g] = ACCIN[g][0]; u1[g] = ACCIN[g][2]; }    \
            short hb[2];                                                                 \
            lstm_cell(u0, u1, cst, hsum, hb);                                            \
            ((short*)&hbA[cur ^ 1][sq0][0])[khb] = hb[0];                                \
            ((short*)&hbA[cur ^ 1][sq1][0])[khb] = hb[1];                                \
        }                                                                                \
        if (ct == 12 && more) {     /* convert + write next chunk to LDS */              \
            bfrag8 o0, o1;                                                               \
            _Pragma("unroll")                                                            \
            for (int j = 0; j < 4; ++j) { o0[j] = f2bf(((float*)&l0)[j]); o0[4+j] = f2bf(((float*)&l1)[j]); } \
            _Pragma("unroll")                                                            \
            for (int j = 0; j < 4; ++j) { o1[j] = f2bf(((float*)&l2)[j]); o1[4+j] = f2bf(((float*)&l3)[j]); } \
            *(bfrag8*)&xs[buf ^ 1][stt][w][sdd]     = o0;                                \
            *(bfrag8*)&xs[buf ^ 1][stt][w][sdd + 8] = o1;                                \
        }                                                                                \
        block_barrier();                                                                 \
        cur ^= 1;                                                                        \
    }

    if (w < 4) {   // ================= group A =================
#pragma unroll 1
        for (int chunk = 0; chunk < LSEQ / CHK; ++chunk) {
            const int buf = chunk & 1;
            const bool more = chunk < (LSEQ / CHK - 1);
            float4 l0, l1, l2, l3;
            bfrag8 xf0, xf1;
#pragma unroll
            for (int ct2 = 0; ct2 < CHK / 2; ++ct2) {
                STEP(accA, accB, 2 * ct2,     1, (ct2 == 0));
                STEP(accB, accA, 2 * ct2 + 1, 1, 0);
            }
        }
    } else {       // ================= group B =================
#pragma unroll 1
        for (int chunk = 0; chunk < LSEQ / CHK; ++chunk) {
            const int buf = chunk & 1;
            const bool more = chunk < (LSEQ / CHK - 1);
            float4 l0, l1, l2, l3;
            bfrag8 xf0, xf1;
#pragma unroll
            for (int ct2 = 0; ct2 < CHK / 2; ++ct2) {
                STEP(accA, accB, 2 * ct2,     0, (ct2 == 0));
                STEP(accB, accA, 2 * ct2 + 1, 0, 0);
            }
        }
        // epilogue: u(127) completed in accB (t=127 had ACCIN=accB), never celled
        {
            float u0[4], u1[4];
#pragma unroll
            for (int g = 0; g < 4; ++g) { u0[g] = accB[g][0]; u1[g] = accB[g][2]; }
            short hb[2];
            lstm_cell(u0, u1, cst, hsum, hb);   // h(128) discarded; hsum final
        }
    }
#undef STEP

    // rep[b][k] = sum_t h_t[b][k] — every lane writes its 2 owned seqs
    rep[(size_t)(s0 + sq0) * HID + khid] = hsum[0];
    rep[(size_t)(s0 + sq1) * HID + khid] = hsum[1];
}

// Epilogue: graph mean over C=32, classifier [10,128], log-softmax -> f32 out[64][10]
__global__ __launch_bounds__(128) void cls_kernel(
    const float* __restrict__ rep,    // [2048][128]
    const float* __restrict__ Wcls,   // [10][128]
    const float* __restrict__ bcls,   // [10]
    float* __restrict__ out)          // [64][10]
{
    __shared__ float m_s[HID];
    __shared__ float logits_s[NCLS];
    const int g = blockIdx.x;
    const int h = threadIdx.x;

    float s = 0.f;
#pragma unroll 4
    for (int c = 0; c < 32; ++c)
        s += rep[((size_t)g * 32 + c) * HID + h];
    m_s[h] = s * (1.0f / 32.0f);
    __syncthreads();

    if (h < NCLS) {
        float acc = bcls[h];
        for (int k = 0; k < HID; ++k)
            acc += m_s[k] * Wcls[h * HID + k];
        logits_s[h] = acc;
    }
    __syncthreads();

    if (h < NCLS) {
        float mx = logits_s[0];
#pragma unroll
        for (int j = 1; j < NCLS; ++j) mx = fmaxf(mx, logits_s[j]);
        float se = 0.f;
#pragma unroll
        for (int j = 0; j < NCLS; ++j)
            se += __builtin_amdgcn_exp2f((logits_s[j] - mx) * 1.4426950408889634f);
        float lse = mx + 0.6931471805599453f * __builtin_amdgcn_logf(se);
        out[g * NCLS + h] = logits_s[h] - lse;
    }
}

extern "C" void kernel_launch(void* const* d_in, const int* in_sizes, int n_in,
                              void* d_out, int out_size, void* d_ws, size_t ws_size,
                              hipStream_t stream) {
    const float* x    = (const float*)d_in[0];
    const float* Wih  = (const float*)d_in[1];
    const float* Whh  = (const float*)d_in[2];
    const float* bih  = (const float*)d_in[3];
    const float* bhh  = (const float*)d_in[4];
    const float* Wcls = (const float*)d_in[5];
    const float* bcls = (const float*)d_in[6];

    float* rep = (float*)d_ws;   // 2048*128 fp32 = 1 MB scratch

    lstm_fused<<<NSEQ / 8, 512, 0, stream>>>(x, Wih, Whh, bih, bhh, rep);
    cls_kernel<<<64, 128, 0, stream>>>(rep, Wcls, bcls, (float*)d_out);
}